// Round 1
// baseline (1286.689 us; speedup 1.0000x reference)
//
#include <hip/hip_runtime.h>
#include <math.h>

typedef float f4 __attribute__((ext_vector_type(4)));

#define PLANE (4096*4096)

// ---- output offsets (floats), concatenated return order ----
#define OUT_COL 0
#define OUT_ROW 262144
#define OUT_OBJ 524288
#define OUT_CV  524352
#define OUT_VC  34078784
#define OUT_VO  67633216
#define OUT_CO  67641408

// ---- workspace offsets (floats) ----
#define WS_VO_P 0        // [16][64] v->o attention per-block partials
#define WS_CO_P 1024     // [16][64] c->o attention per-block partials
#define WS_OBJ1 2048     // [64]  obj after v->o update
#define WS_RDCV 2112     // [4096] row_hidden . w_cv_row
#define WS_CDCV 6208     // [4096] col_hidden . w_cv_col
#define WS_RDVC 10304    // [4096] row_next . w_vc_row
#define WS_CDVC 14400    // [4096] col_hidden . w_vc_col
#define WS_PART 18496    // [16][4096*64] j-split partials (16 MB now)

__device__ __forceinline__ float sigf(float x) {
    return 1.0f / (1.0f + __expf(-x));
}

// score-tile LDS swizzle: rows {r, r+4, r+8, r+12} are read together by one
// wave instruction; with a [64][64]-f4 linear layout they'd alias to the same
// banks (stride 1KB). XOR the f4-column with ((row>>2)&3)<<1 -> 4 distinct
// bank groups, conflict-free, no padding (keeps LDS at exactly 80KB).
#define SSWZ(row, f4col) (((row) << 6) + ((f4col) ^ ((((row) >> 2) & 3) << 1)))

// ---------------------------------------------------------------------------
// Attention body over 4096 nodes (one 256-thread block handles 256 nodes):
//   a[i] = sigmoid(X[i].wat[0:64] + supp[i].wat[64:66] + obj.wat[66:130] + b)
//   accP[blk][h] = sum_{i in blk} a[i]*X[i,h]   (per-block partial, no atomics)
// Optionally dextra[i] = X[i].wextra (fused row_next . w_vc_row).
__device__ __forceinline__ void attn_body(
    int blk, int t, const float* __restrict__ X, const float* __restrict__ supp,
    const float* __restrict__ obj, const float* __restrict__ wat,
    const float* __restrict__ bat, float* __restrict__ accP,
    const float* __restrict__ wextra, float* __restrict__ dextra,
    float* sA, float* sAcc)
{
    const int i = blk * 256 + t;
    float od = 0.f;
    for (int h = 0; h < 64; ++h) od += obj[h] * wat[66 + h];
    float x = bat[0] + od + supp[i*2] * wat[64] + supp[i*2+1] * wat[65];
    const f4* Xr = (const f4*)(X + i*64);
    f4 xd = 0.f, dd = 0.f;
    #pragma unroll
    for (int q = 0; q < 16; ++q) {
        f4 xv = Xr[q];
        xd += xv * ((const f4*)wat)[q];
        if (wextra) dd += xv * ((const f4*)wextra)[q];
    }
    x += xd.x + xd.y + xd.z + xd.w;
    if (dextra) dextra[i] = dd.x + dd.y + dd.z + dd.w;
    sA[t] = sigf(x);
    if (t < 64) sAcc[t] = 0.f;
    __syncthreads();
    const int w = t >> 6, h = t & 63;
    const int base = blk * 256 + w * 64;
    float partial = 0.f;
    for (int j = 0; j < 64; ++j)
        partial += sA[w*64 + j] * X[(base + j)*64 + h];
    atomicAdd(&sAcc[h], partial);
    __syncthreads();
    if (t < 64) accP[blk*64 + t] = sAcc[t];
}

// ---------------------------------------------------------------------------
// Front kernel: 3072 dot blocks + 16 small-copy blocks + 16 v->o attention blocks.
__global__ __launch_bounds__(256) void k_front(
    const float* __restrict__ col_hidden, const float* __restrict__ row_hidden,
    const float* __restrict__ w_cv_col, const float* __restrict__ w_vc_col,
    const float* __restrict__ w_cv_row,
    float* __restrict__ cdcv, float* __restrict__ cdvc, float* __restrict__ rdcv,
    const float* __restrict__ vo_supp, const float* __restrict__ co_supp,
    float* __restrict__ out_vo, float* __restrict__ out_co,
    const float* __restrict__ obj_hidden, const float* __restrict__ w_attn_vo,
    const float* __restrict__ b_attn_vo, float* __restrict__ voP)
{
    __shared__ float sA[256];
    __shared__ float sAcc[64];
    const int t = threadIdx.x;
    if (blockIdx.x < 3072) {
        const int gw = blockIdx.x * 4 + (t >> 6);
        const int lane = t & 63;
        const int which = gw >> 12;       // 0,1,2
        const int row = gw & 4095;
        const float* x; const float* w; float* dst;
        if (which == 0)      { x = col_hidden; w = w_cv_col; dst = cdcv; }
        else if (which == 1) { x = col_hidden; w = w_vc_col; dst = cdvc; }
        else                 { x = row_hidden; w = w_cv_row; dst = rdcv; }
        float v = x[row * 64 + lane] * w[lane];
        #pragma unroll
        for (int off = 32; off; off >>= 1) v += __shfl_down(v, off, 64);
        if (lane == 0) dst[row] = v;
        return;
    }
    if (blockIdx.x < 3088) {
        const int idx = (blockIdx.x - 3072) * 256 + t;   // 0..4095 f4 units
        if (idx < 2048) ((f4*)out_vo)[idx] = ((const f4*)vo_supp)[idx];
        else            ((f4*)out_co)[idx - 2048] = ((const f4*)co_supp)[idx - 2048];
        return;
    }
    attn_body(blockIdx.x - 3088, t, col_hidden, vo_supp, obj_hidden,
              w_attn_vo, b_attn_vo, voP, nullptr, nullptr, sA, sAcc);
}

// ---------------------------------------------------------------------------
// Standalone c->o attention (16 blocks), with fused rowdot_vc.
__global__ __launch_bounds__(256) void k_attn(
    const float* __restrict__ X, const float* __restrict__ supp,
    const float* __restrict__ obj, const float* __restrict__ wat,
    const float* __restrict__ bat, float* __restrict__ accP,
    const float* __restrict__ wextra, float* __restrict__ dextra)
{
    __shared__ float sA[256];
    __shared__ float sAcc[64];
    attn_body(blockIdx.x, threadIdx.x, X, supp, obj, wat, bat, accP,
              wextra, dextra, sA, sAcc);
}

// ---------------------------------------------------------------------------
// Big fused kernel: masked pairwise sigmoid scores + score @ B + supp passthrough.
//   out(i,h) = sum_j [supp0(i,j)!=0] sig(rdot[i]+cdot[j]+w0*supp0+w1*supp1+b) * B(j,h)
// R5 theory: prior 64x64 tile capped per-instruction contiguity at 4x256B
// scattered bursts (ilb = t>>4 -> 4 rows per vmem op at 16KB stride), which is
// the "DRAM address stream" limiter identified in R4 (invariant ~150us @
// 2.2 TB/s). This version uses a 64x256 tile staged so ONE WAVE INSTRUCTION
// READS/WRITES ONE FULL 1KB ROW SEGMENT (lane = col/4, wave = row). j-splits
// drop 64->16, shrinking part 64MB->16MB. LDS = 64KB score (XOR-swizzled, no
// pad) + 16KB B sub-tile = 80KB -> 2 blocks/CU. grid = 64*16 + 1 = 1025.
__global__ __launch_bounds__(256, 2) void k_big(
    const float* __restrict__ supp0, const float* __restrict__ supp1,
    const float* __restrict__ Bm,
    const float* __restrict__ rdot, const float* __restrict__ cdot,
    const float* __restrict__ wsup, const float* __restrict__ bias,
    float* __restrict__ part, float* __restrict__ pass0, float* __restrict__ pass1,
    const float* __restrict__ objL, const float* __restrict__ objRp,
    const float* __restrict__ Wobj, float* __restrict__ objDst)
{
    __shared__ __align__(16) f4 sS[4096];        // 64KB score tile, swizzled
    __shared__ __align__(16) float sB[64][64];   // 16KB B sub-tile
    const int t = threadIdx.x;

    if (blockIdx.x == 1024) {
        // obj update: objDst[h] = relu([objL | sum_b objRp[b]] @ Wobj)
        float* rsum = (float*)sS;
        if (t < 64) {
            float r = 0.f;
            for (int b = 0; b < 16; ++b) r += objRp[b*64 + t];
            rsum[t] = r;
        }
        __syncthreads();
        if (t < 64) {
            float acc = 0.f;
            for (int k = 0; k < 64; ++k) acc += objL[k] * Wobj[k*64 + t];
            for (int k = 0; k < 64; ++k) acc += rsum[k] * Wobj[(64+k)*64 + t];
            objDst[t] = fmaxf(acc, 0.f);
        }
        return;
    }

    const int bi = blockIdx.x >> 4;       // SLOW index: row-block 0..63
    const int bj = blockIdx.x & 15;       // FAST index: j-split 0..15
    const int i0 = bi * 64;
    const int jt0 = bj * 256;
    const float w0 = wsup[0], w1 = wsup[1], bv = bias[0];

    // ---- stage: scores for the full 64x256 tile + fused passthrough ----
    // wave w, iter q handles row q*4+w, lane l handles cols l*4..l*4+3:
    // every supp load / pass store is a single contiguous 1KB wave burst.
    const int srow = t >> 6;              // wave id 0..3
    const int sf4  = t & 63;              // f4-column 0..63
    const int scol = sf4 * 4;
    const f4 cd = *(const f4*)(cdot + jt0 + scol);
    #pragma unroll
    for (int q = 0; q < 16; ++q) {
        const int row = q*4 + srow;
        const size_t idx = (size_t)(i0 + row) * 4096 + jt0 + scol;
        f4 a0 = *(const f4*)(supp0 + idx);
        f4 a1 = *(const f4*)(supp1 + idx);
        __builtin_nontemporal_store(a0, (f4*)(pass0 + idx));
        __builtin_nontemporal_store(a1, (f4*)(pass1 + idx));
        const float rd = rdot[i0 + row];
        f4 lg = rd + cd + w0*a0 + w1*a1 + bv;
        f4 s;
        s.x = (a0.x != 0.f) ? sigf(lg.x) : 0.f;
        s.y = (a0.y != 0.f) ? sigf(lg.y) : 0.f;
        s.z = (a0.z != 0.f) ? sigf(lg.z) : 0.f;
        s.w = (a0.w != 0.f) ? sigf(lg.w) : 0.f;
        sS[SSWZ(row, sf4)] = s;
    }
    // stage B sub-tile 0 (contiguous 16KB, L2-hot)
    {
        const f4* src = (const f4*)(Bm + (size_t)jt0 * 64);
        f4* dstp = (f4*)&sB[0][0];
        dstp[t]       = src[t];
        dstp[t + 256] = src[t + 256];
        dstp[t + 512] = src[t + 512];
        dstp[t + 768] = src[t + 768];
    }
    __syncthreads();

    // ---- rank-256 update, 4 sub-tiles of 64 j each, acc carried across ----
    const int ilb = t >> 4;               // 0..15 -> rows ilb*4..+3
    const int h0  = (t & 15) * 4;
    f4 acc0 = 0.f, acc1 = 0.f, acc2 = 0.f, acc3 = 0.f;
    for (int q4 = 0; q4 < 4; ++q4) {
        // prefetch next B sub-tile into regs; latency hides under compute
        f4 nb0, nb1, nb2, nb3;
        if (q4 < 3) {
            const f4* src = (const f4*)(Bm + (size_t)(jt0 + (q4+1)*64) * 64);
            nb0 = src[t]; nb1 = src[t + 256]; nb2 = src[t + 512]; nb3 = src[t + 768];
        }
        const int c4 = q4 * 16;
        #pragma unroll
        for (int jf = 0; jf < 16; ++jf) {
            const int jj = jf * 4;
            f4 b0 = *(const f4*)&sB[jj + 0][h0];
            f4 b1 = *(const f4*)&sB[jj + 1][h0];
            f4 b2 = *(const f4*)&sB[jj + 2][h0];
            f4 b3 = *(const f4*)&sB[jj + 3][h0];
            { f4 s = sS[SSWZ(ilb*4 + 0, c4 + jf)]; acc0 += s.x*b0 + s.y*b1 + s.z*b2 + s.w*b3; }
            { f4 s = sS[SSWZ(ilb*4 + 1, c4 + jf)]; acc1 += s.x*b0 + s.y*b1 + s.z*b2 + s.w*b3; }
            { f4 s = sS[SSWZ(ilb*4 + 2, c4 + jf)]; acc2 += s.x*b0 + s.y*b1 + s.z*b2 + s.w*b3; }
            { f4 s = sS[SSWZ(ilb*4 + 3, c4 + jf)]; acc3 += s.x*b0 + s.y*b1 + s.z*b2 + s.w*b3; }
        }
        if (q4 < 3) {
            __syncthreads();
            f4* dstp = (f4*)&sB[0][0];
            dstp[t] = nb0; dstp[t + 256] = nb1; dstp[t + 512] = nb2; dstp[t + 768] = nb3;
            __syncthreads();
        }
    }
    // partials: regular stores (re-read next dispatch — let L2/L3 keep them)
    float* pb = part + (size_t)bj * 262144 + (size_t)i0 * 64;
    *(f4*)(pb + (ilb*4 + 0)*64 + h0) = acc0;
    *(f4*)(pb + (ilb*4 + 1)*64 + h0) = acc1;
    *(f4*)(pb + (ilb*4 + 2)*64 + h0) = acc2;
    *(f4*)(pb + (ilb*4 + 3)*64 + h0) = acc3;
}

// ---------------------------------------------------------------------------
// Two-layer node update with fused 16-way partial reduction:
//   accin[n] = sum_j part[j][n]
//   mid = relu([objx | base[n]] @ W1);  dst[n] = relu([mid | accin[n]] @ W2)
// One wave per node row; grid = 1024 blocks x 256.
__global__ __launch_bounds__(256) void k_mlp2(
    const float* __restrict__ objx, const float* __restrict__ base,
    const float* __restrict__ W1, const float* __restrict__ part,
    const float* __restrict__ W2, float* __restrict__ dst)
{
    __shared__ float mid[4][64];
    __shared__ float accs[4][64];
    const int t = threadIdx.x, w = t >> 6, h = t & 63;
    const int n = blockIdx.x * 4 + w;
    float v = 0.f;
    #pragma unroll
    for (int j = 0; j < 16; ++j) v += part[(size_t)j * 262144 + n*64 + h];
    accs[w][h] = v;
    float m = 0.f;
    for (int k = 0; k < 64; ++k) m += objx[k] * W1[k*64 + h];
    for (int k = 0; k < 64; ++k) m += base[n*64 + k] * W1[(64+k)*64 + h];
    mid[w][h] = fmaxf(m, 0.f);
    __syncthreads();
    float o = 0.f;
    for (int k = 0; k < 64; ++k) o += mid[w][k] * W2[k*64 + h];
    for (int k = 0; k < 64; ++k) o += accs[w][k] * W2[(64+k)*64 + h];
    dst[n*64 + h] = fmaxf(o, 0.f);
}

extern "C" void kernel_launch(void* const* d_in, const int* in_sizes, int n_in,
                              void* d_out, int out_size, void* d_ws, size_t ws_size,
                              hipStream_t stream)
{
    const float* col_hidden = (const float*)d_in[0];
    const float* row_hidden = (const float*)d_in[1];
    const float* obj_hidden = (const float*)d_in[2];
    const float* cv_supp    = (const float*)d_in[3];
    const float* vc_supp    = (const float*)d_in[4];
    const float* vo_supp    = (const float*)d_in[5];
    const float* co_supp    = (const float*)d_in[6];
    const float* W_vo       = (const float*)d_in[7];
    const float* W_oc       = (const float*)d_in[8];
    const float* W_vc       = (const float*)d_in[9];
    const float* W_co       = (const float*)d_in[10];
    const float* W_ov       = (const float*)d_in[11];
    const float* W_cv       = (const float*)d_in[12];
    const float* w_attn_vo  = (const float*)d_in[13];
    const float* b_attn_vo  = (const float*)d_in[14];
    const float* w_attn_co  = (const float*)d_in[15];
    const float* b_attn_co  = (const float*)d_in[16];
    const float* w_cv_col   = (const float*)d_in[17];
    const float* w_cv_supp  = (const float*)d_in[18];
    const float* w_cv_row   = (const float*)d_in[19];
    const float* b_cv       = (const float*)d_in[20];
    const float* w_vc_row   = (const float*)d_in[21];
    const float* w_vc_supp  = (const float*)d_in[22];
    const float* w_vc_col   = (const float*)d_in[23];
    const float* b_vc       = (const float*)d_in[24];

    float* out = (float*)d_out;
    float* ws  = (float*)d_ws;

    // 1) dots + small passthrough + v->o attention partials
    k_front<<<3104, 256, 0, stream>>>(col_hidden, row_hidden, w_cv_col, w_vc_col, w_cv_row,
                                      ws + WS_CDCV, ws + WS_CDVC, ws + WS_RDCV,
                                      vo_supp, co_supp, out + OUT_VO, out + OUT_CO,
                                      obj_hidden, w_attn_vo, b_attn_vo, ws + WS_VO_P);
    // 2) v->c big masked matmul (+ fused cv_supp passthrough, + obj v->o update)
    k_big<<<1025, 256, 0, stream>>>(cv_supp, cv_supp + PLANE, col_hidden,
                                    ws + WS_RDCV, ws + WS_CDCV, w_cv_supp, b_cv,
                                    ws + WS_PART, out + OUT_CV, out + OUT_CV + PLANE,
                                    obj_hidden, ws + WS_VO_P, W_vo, ws + WS_OBJ1);
    // 3) row_next = relu([relu([obj1|row_hidden]W_oc) | v_out] W_vc)
    k_mlp2<<<1024, 256, 0, stream>>>(ws + WS_OBJ1, row_hidden, W_oc, ws + WS_PART, W_vc,
                                     out + OUT_ROW);
    // 4) c->o attention partials (+ fused rowdot_vc over row_next)
    k_attn<<<16, 256, 0, stream>>>(out + OUT_ROW, co_supp, ws + WS_OBJ1, w_attn_co, b_attn_co,
                                   ws + WS_CO_P, w_vc_row, ws + WS_RDVC);
    // 5) c->v big masked matmul (+ fused vc_supp passthrough, + obj c->o update)
    k_big<<<1025, 256, 0, stream>>>(vc_supp, vc_supp + PLANE, out + OUT_ROW,
                                    ws + WS_CDVC, ws + WS_RDVC, w_vc_supp, b_vc,
                                    ws + WS_PART, out + OUT_VC, out + OUT_VC + PLANE,
                                    ws + WS_OBJ1, ws + WS_CO_P, W_co, out + OUT_OBJ);
    // 6) col_next = relu([relu([obj|col_hidden]W_ov) | c_out] W_cv)
    k_mlp2<<<1024, 256, 0, stream>>>(out + OUT_OBJ, col_hidden, W_ov, ws + WS_PART, W_cv,
                                     out + OUT_COL);
}

// Round 2
// 606.550 us; speedup vs baseline: 2.1213x; 2.1213x over previous
//
#include <hip/hip_runtime.h>
#include <math.h>

typedef float f4 __attribute__((ext_vector_type(4)));

#define PLANE (4096*4096)

// ---- output offsets (floats), concatenated return order ----
#define OUT_COL 0
#define OUT_ROW 262144
#define OUT_OBJ 524288
#define OUT_CV  524352
#define OUT_VC  34078784
#define OUT_VO  67633216
#define OUT_CO  67641408

// ---- workspace offsets (floats) ----
#define WS_VO_P 0        // [16][64] v->o attention per-block partials
#define WS_CO_P 1024     // [16][64] c->o attention per-block partials
#define WS_OBJ1 2048     // [64]  obj after v->o update
#define WS_RDCV 2112     // [4096] row_hidden . w_cv_row
#define WS_CDCV 6208     // [4096] col_hidden . w_cv_col
#define WS_RDVC 10304    // [4096] row_next . w_vc_row
#define WS_CDVC 14400    // [4096] col_hidden . w_vc_col
#define WS_PART 18496    // [16][4096*64] j-split partials (16 MB)

__device__ __forceinline__ float sigf(float x) {
    return 1.0f / (1.0f + __expf(-x));
}

// score-tile LDS swizzle: rows {r, r+4, r+8, r+12} are read together by one
// wave instruction; with a [64][64]-f4 linear layout they'd alias to the same
// banks (stride 1KB). XOR the f4-column with ((row>>2)&3)<<1 -> 4 distinct
// bank groups, conflict-free, no padding (keeps LDS at exactly 80KB).
#define SSWZ(row, f4col) (((row) << 6) + ((f4col) ^ ((((row) >> 2) & 3) << 1)))

// ---------------------------------------------------------------------------
// Attention body over 4096 nodes (one 256-thread block handles 256 nodes):
//   a[i] = sigmoid(X[i].wat[0:64] + supp[i].wat[64:66] + obj.wat[66:130] + b)
//   accP[blk][h] = sum_{i in blk} a[i]*X[i,h]   (per-block partial, no atomics)
// Optionally dextra[i] = X[i].wextra (fused row_next . w_vc_row).
__device__ __forceinline__ void attn_body(
    int blk, int t, const float* __restrict__ X, const float* __restrict__ supp,
    const float* __restrict__ obj, const float* __restrict__ wat,
    const float* __restrict__ bat, float* __restrict__ accP,
    const float* __restrict__ wextra, float* __restrict__ dextra,
    float* sA, float* sAcc)
{
    const int i = blk * 256 + t;
    float od = 0.f;
    for (int h = 0; h < 64; ++h) od += obj[h] * wat[66 + h];
    float x = bat[0] + od + supp[i*2] * wat[64] + supp[i*2+1] * wat[65];
    const f4* Xr = (const f4*)(X + i*64);
    f4 xd = 0.f, dd = 0.f;
    #pragma unroll
    for (int q = 0; q < 16; ++q) {
        f4 xv = Xr[q];
        xd += xv * ((const f4*)wat)[q];
        if (wextra) dd += xv * ((const f4*)wextra)[q];
    }
    x += xd.x + xd.y + xd.z + xd.w;
    if (dextra) dextra[i] = dd.x + dd.y + dd.z + dd.w;
    sA[t] = sigf(x);
    if (t < 64) sAcc[t] = 0.f;
    __syncthreads();
    const int w = t >> 6, h = t & 63;
    const int base = blk * 256 + w * 64;
    float partial = 0.f;
    for (int j = 0; j < 64; ++j)
        partial += sA[w*64 + j] * X[(base + j)*64 + h];
    atomicAdd(&sAcc[h], partial);
    __syncthreads();
    if (t < 64) accP[blk*64 + t] = sAcc[t];
}

// ---------------------------------------------------------------------------
// Front kernel: 3072 dot blocks + 16 small-copy blocks + 16 v->o attention blocks.
__global__ __launch_bounds__(256) void k_front(
    const float* __restrict__ col_hidden, const float* __restrict__ row_hidden,
    const float* __restrict__ w_cv_col, const float* __restrict__ w_vc_col,
    const float* __restrict__ w_cv_row,
    float* __restrict__ cdcv, float* __restrict__ cdvc, float* __restrict__ rdcv,
    const float* __restrict__ vo_supp, const float* __restrict__ co_supp,
    float* __restrict__ out_vo, float* __restrict__ out_co,
    const float* __restrict__ obj_hidden, const float* __restrict__ w_attn_vo,
    const float* __restrict__ b_attn_vo, float* __restrict__ voP)
{
    __shared__ float sA[256];
    __shared__ float sAcc[64];
    const int t = threadIdx.x;
    if (blockIdx.x < 3072) {
        const int gw = blockIdx.x * 4 + (t >> 6);
        const int lane = t & 63;
        const int which = gw >> 12;       // 0,1,2
        const int row = gw & 4095;
        const float* x; const float* w; float* dst;
        if (which == 0)      { x = col_hidden; w = w_cv_col; dst = cdcv; }
        else if (which == 1) { x = col_hidden; w = w_vc_col; dst = cdvc; }
        else                 { x = row_hidden; w = w_cv_row; dst = rdcv; }
        float v = x[row * 64 + lane] * w[lane];
        #pragma unroll
        for (int off = 32; off; off >>= 1) v += __shfl_down(v, off, 64);
        if (lane == 0) dst[row] = v;
        return;
    }
    if (blockIdx.x < 3088) {
        const int idx = (blockIdx.x - 3072) * 256 + t;   // 0..4095 f4 units
        if (idx < 2048) ((f4*)out_vo)[idx] = ((const f4*)vo_supp)[idx];
        else            ((f4*)out_co)[idx - 2048] = ((const f4*)co_supp)[idx - 2048];
        return;
    }
    attn_body(blockIdx.x - 3088, t, col_hidden, vo_supp, obj_hidden,
              w_attn_vo, b_attn_vo, voP, nullptr, nullptr, sA, sAcc);
}

// ---------------------------------------------------------------------------
// Standalone c->o attention (16 blocks), with fused rowdot_vc.
__global__ __launch_bounds__(256) void k_attn(
    const float* __restrict__ X, const float* __restrict__ supp,
    const float* __restrict__ obj, const float* __restrict__ wat,
    const float* __restrict__ bat, float* __restrict__ accP,
    const float* __restrict__ wextra, float* __restrict__ dextra)
{
    __shared__ float sA[256];
    __shared__ float sAcc[64];
    attn_body(blockIdx.x, threadIdx.x, X, supp, obj, wat, bat, accP,
              wextra, dextra, sA, sAcc);
}

// ---------------------------------------------------------------------------
// Big fused kernel: masked pairwise sigmoid scores + score @ B + supp passthrough.
//   out(i,h) = sum_j [supp0(i,j)!=0] sig(rdot[i]+cdot[j]+w0*supp0+w1*supp1+b) * B(j,h)
// 64x256 tile, staged so ONE WAVE INSTRUCTION READS/WRITES ONE FULL 1KB ROW
// SEGMENT (lane = col/4, wave = row). R1 counters validated the burst theory
// (4.4 TB/s effective vs 2.2 for 64x64) but showed 6x traffic amplification
// (2.09 GB/dispatch vs 350 MB algorithmic) -> loop-resident scratch spill from
// (a) full unroll-16 staging (128 data VGPRs in flight) and (b) B-prefetch
// registers held across the 16-step FMA loop. R2 FIX: staging unroll capped
// at 4 (proven depth from the 64x64 kernel), B re-staged from L2 between
// barriers instead of register prefetch. Nothing else changed.
// grid = 64 row-blocks * 16 j-splits + 1 = 1025.
__global__ __launch_bounds__(256, 2) void k_big(
    const float* __restrict__ supp0, const float* __restrict__ supp1,
    const float* __restrict__ Bm,
    const float* __restrict__ rdot, const float* __restrict__ cdot,
    const float* __restrict__ wsup, const float* __restrict__ bias,
    float* __restrict__ part, float* __restrict__ pass0, float* __restrict__ pass1,
    const float* __restrict__ objL, const float* __restrict__ objRp,
    const float* __restrict__ Wobj, float* __restrict__ objDst)
{
    __shared__ __align__(16) f4 sS[4096];        // 64KB score tile, swizzled
    __shared__ __align__(16) float sB[64][64];   // 16KB B sub-tile
    const int t = threadIdx.x;

    if (blockIdx.x == 1024) {
        // obj update: objDst[h] = relu([objL | sum_b objRp[b]] @ Wobj)
        float* rsum = (float*)sS;
        if (t < 64) {
            float r = 0.f;
            for (int b = 0; b < 16; ++b) r += objRp[b*64 + t];
            rsum[t] = r;
        }
        __syncthreads();
        if (t < 64) {
            float acc = 0.f;
            for (int k = 0; k < 64; ++k) acc += objL[k] * Wobj[k*64 + t];
            for (int k = 0; k < 64; ++k) acc += rsum[k] * Wobj[(64+k)*64 + t];
            objDst[t] = fmaxf(acc, 0.f);
        }
        return;
    }

    const int bi = blockIdx.x >> 4;       // SLOW index: row-block 0..63
    const int bj = blockIdx.x & 15;       // FAST index: j-split 0..15
    const int i0 = bi * 64;
    const int jt0 = bj * 256;
    const float w0 = wsup[0], w1 = wsup[1], bv = bias[0];

    // ---- stage: scores for the full 64x256 tile + fused passthrough ----
    // wave w, iter q handles row q*4+w, lane l handles cols l*4..l*4+3:
    // every supp load / pass store is a single contiguous 1KB wave burst.
    // unroll 4 ONLY: caps in-flight load data at 32 VGPRs (spill guard).
    const int srow = t >> 6;              // wave id 0..3
    const int sf4  = t & 63;              // f4-column 0..63
    const int scol = sf4 * 4;
    const f4 cd = *(const f4*)(cdot + jt0 + scol);
    #pragma unroll 4
    for (int q = 0; q < 16; ++q) {
        const int row = q*4 + srow;
        const size_t idx = (size_t)(i0 + row) * 4096 + jt0 + scol;
        f4 a0 = *(const f4*)(supp0 + idx);
        f4 a1 = *(const f4*)(supp1 + idx);
        __builtin_nontemporal_store(a0, (f4*)(pass0 + idx));
        __builtin_nontemporal_store(a1, (f4*)(pass1 + idx));
        const float rd = rdot[i0 + row];
        f4 lg = rd + cd + w0*a0 + w1*a1 + bv;
        f4 s;
        s.x = (a0.x != 0.f) ? sigf(lg.x) : 0.f;
        s.y = (a0.y != 0.f) ? sigf(lg.y) : 0.f;
        s.z = (a0.z != 0.f) ? sigf(lg.z) : 0.f;
        s.w = (a0.w != 0.f) ? sigf(lg.w) : 0.f;
        sS[SSWZ(row, sf4)] = s;
    }
    // stage B sub-tile 0 (contiguous 16KB, L2-hot)
    {
        const f4* src = (const f4*)(Bm + (size_t)jt0 * 64);
        f4* dstp = (f4*)&sB[0][0];
        dstp[t]       = src[t];
        dstp[t + 256] = src[t + 256];
        dstp[t + 512] = src[t + 512];
        dstp[t + 768] = src[t + 768];
    }
    __syncthreads();

    // ---- rank-256 update, 4 sub-tiles of 64 j each, acc carried across ----
    // sB re-staged from global (L2-hot, 1 MiB matrix) between barriers: no
    // long-lived prefetch registers.
    const int ilb = t >> 4;               // 0..15 -> rows ilb*4..+3
    const int h0  = (t & 15) * 4;
    f4 acc0 = 0.f, acc1 = 0.f, acc2 = 0.f, acc3 = 0.f;
    for (int q4 = 0; q4 < 4; ++q4) {
        if (q4) {
            __syncthreads();   // everyone done with previous sB
            const f4* src = (const f4*)(Bm + (size_t)(jt0 + q4*64) * 64);
            f4* dstp = (f4*)&sB[0][0];
            dstp[t]       = src[t];
            dstp[t + 256] = src[t + 256];
            dstp[t + 512] = src[t + 512];
            dstp[t + 768] = src[t + 768];
            __syncthreads();   // new sB visible
        }
        const int c4 = q4 * 16;
        #pragma unroll
        for (int jf = 0; jf < 16; ++jf) {
            const int jj = jf * 4;
            f4 b0 = *(const f4*)&sB[jj + 0][h0];
            f4 b1 = *(const f4*)&sB[jj + 1][h0];
            f4 b2 = *(const f4*)&sB[jj + 2][h0];
            f4 b3 = *(const f4*)&sB[jj + 3][h0];
            { f4 s = sS[SSWZ(ilb*4 + 0, c4 + jf)]; acc0 += s.x*b0 + s.y*b1 + s.z*b2 + s.w*b3; }
            { f4 s = sS[SSWZ(ilb*4 + 1, c4 + jf)]; acc1 += s.x*b0 + s.y*b1 + s.z*b2 + s.w*b3; }
            { f4 s = sS[SSWZ(ilb*4 + 2, c4 + jf)]; acc2 += s.x*b0 + s.y*b1 + s.z*b2 + s.w*b3; }
            { f4 s = sS[SSWZ(ilb*4 + 3, c4 + jf)]; acc3 += s.x*b0 + s.y*b1 + s.z*b2 + s.w*b3; }
        }
    }
    // partials: regular stores (re-read next dispatch — let L2/L3 keep them)
    float* pb = part + (size_t)bj * 262144 + (size_t)i0 * 64;
    *(f4*)(pb + (ilb*4 + 0)*64 + h0) = acc0;
    *(f4*)(pb + (ilb*4 + 1)*64 + h0) = acc1;
    *(f4*)(pb + (ilb*4 + 2)*64 + h0) = acc2;
    *(f4*)(pb + (ilb*4 + 3)*64 + h0) = acc3;
}

// ---------------------------------------------------------------------------
// Two-layer node update with fused 16-way partial reduction:
//   accin[n] = sum_j part[j][n]
//   mid = relu([objx | base[n]] @ W1);  dst[n] = relu([mid | accin[n]] @ W2)
// One wave per node row; grid = 1024 blocks x 256.
__global__ __launch_bounds__(256) void k_mlp2(
    const float* __restrict__ objx, const float* __restrict__ base,
    const float* __restrict__ W1, const float* __restrict__ part,
    const float* __restrict__ W2, float* __restrict__ dst)
{
    __shared__ float mid[4][64];
    __shared__ float accs[4][64];
    const int t = threadIdx.x, w = t >> 6, h = t & 63;
    const int n = blockIdx.x * 4 + w;
    float v = 0.f;
    #pragma unroll
    for (int j = 0; j < 16; ++j) v += part[(size_t)j * 262144 + n*64 + h];
    accs[w][h] = v;
    float m = 0.f;
    for (int k = 0; k < 64; ++k) m += objx[k] * W1[k*64 + h];
    for (int k = 0; k < 64; ++k) m += base[n*64 + k] * W1[(64+k)*64 + h];
    mid[w][h] = fmaxf(m, 0.f);
    __syncthreads();
    float o = 0.f;
    for (int k = 0; k < 64; ++k) o += mid[w][k] * W2[k*64 + h];
    for (int k = 0; k < 64; ++k) o += accs[w][k] * W2[(64+k)*64 + h];
    dst[n*64 + h] = fmaxf(o, 0.f);
}

extern "C" void kernel_launch(void* const* d_in, const int* in_sizes, int n_in,
                              void* d_out, int out_size, void* d_ws, size_t ws_size,
                              hipStream_t stream)
{
    const float* col_hidden = (const float*)d_in[0];
    const float* row_hidden = (const float*)d_in[1];
    const float* obj_hidden = (const float*)d_in[2];
    const float* cv_supp    = (const float*)d_in[3];
    const float* vc_supp    = (const float*)d_in[4];
    const float* vo_supp    = (const float*)d_in[5];
    const float* co_supp    = (const float*)d_in[6];
    const float* W_vo       = (const float*)d_in[7];
    const float* W_oc       = (const float*)d_in[8];
    const float* W_vc       = (const float*)d_in[9];
    const float* W_co       = (const float*)d_in[10];
    const float* W_ov       = (const float*)d_in[11];
    const float* W_cv       = (const float*)d_in[12];
    const float* w_attn_vo  = (const float*)d_in[13];
    const float* b_attn_vo  = (const float*)d_in[14];
    const float* w_attn_co  = (const float*)d_in[15];
    const float* b_attn_co  = (const float*)d_in[16];
    const float* w_cv_col   = (const float*)d_in[17];
    const float* w_cv_supp  = (const float*)d_in[18];
    const float* w_cv_row   = (const float*)d_in[19];
    const float* b_cv       = (const float*)d_in[20];
    const float* w_vc_row   = (const float*)d_in[21];
    const float* w_vc_supp  = (const float*)d_in[22];
    const float* w_vc_col   = (const float*)d_in[23];
    const float* b_vc       = (const float*)d_in[24];

    float* out = (float*)d_out;
    float* ws  = (float*)d_ws;

    // 1) dots + small passthrough + v->o attention partials
    k_front<<<3104, 256, 0, stream>>>(col_hidden, row_hidden, w_cv_col, w_vc_col, w_cv_row,
                                      ws + WS_CDCV, ws + WS_CDVC, ws + WS_RDCV,
                                      vo_supp, co_supp, out + OUT_VO, out + OUT_CO,
                                      obj_hidden, w_attn_vo, b_attn_vo, ws + WS_VO_P);
    // 2) v->c big masked matmul (+ fused cv_supp passthrough, + obj v->o update)
    k_big<<<1025, 256, 0, stream>>>(cv_supp, cv_supp + PLANE, col_hidden,
                                    ws + WS_RDCV, ws + WS_CDCV, w_cv_supp, b_cv,
                                    ws + WS_PART, out + OUT_CV, out + OUT_CV + PLANE,
                                    obj_hidden, ws + WS_VO_P, W_vo, ws + WS_OBJ1);
    // 3) row_next = relu([relu([obj1|row_hidden]W_oc) | v_out] W_vc)
    k_mlp2<<<1024, 256, 0, stream>>>(ws + WS_OBJ1, row_hidden, W_oc, ws + WS_PART, W_vc,
                                     out + OUT_ROW);
    // 4) c->o attention partials (+ fused rowdot_vc over row_next)
    k_attn<<<16, 256, 0, stream>>>(out + OUT_ROW, co_supp, ws + WS_OBJ1, w_attn_co, b_attn_co,
                                   ws + WS_CO_P, w_vc_row, ws + WS_RDVC);
    // 5) c->v big masked matmul (+ fused vc_supp passthrough, + obj c->o update)
    k_big<<<1025, 256, 0, stream>>>(vc_supp, vc_supp + PLANE, out + OUT_ROW,
                                    ws + WS_CDVC, ws + WS_RDVC, w_vc_supp, b_vc,
                                    ws + WS_PART, out + OUT_VC, out + OUT_VC + PLANE,
                                    ws + WS_OBJ1, ws + WS_CO_P, W_co, out + OUT_OBJ);
    // 6) col_next = relu([relu([obj|col_hidden]W_ov) | c_out] W_cv)
    k_mlp2<<<1024, 256, 0, stream>>>(out + OUT_OBJ, col_hidden, W_ov, ws + WS_PART, W_cv,
                                     out + OUT_COL);
}

// Round 3
// 577.185 us; speedup vs baseline: 2.2292x; 1.0509x over previous
//
#include <hip/hip_runtime.h>
#include <math.h>

typedef float f4 __attribute__((ext_vector_type(4)));

#define PLANE (4096*4096)

// ---- output offsets (floats), concatenated return order ----
#define OUT_COL 0
#define OUT_ROW 262144
#define OUT_OBJ 524288
#define OUT_CV  524352
#define OUT_VC  34078784
#define OUT_VO  67633216
#define OUT_CO  67641408

// ---- workspace offsets (floats) ----
#define WS_VO_P 0        // [16][64] v->o attention per-block partials
#define WS_CO_P 1024     // [16][64] c->o attention per-block partials
#define WS_OBJ1 2048     // [64]  obj after v->o update
#define WS_RDCV 2112     // [4096] row_hidden . w_cv_row
#define WS_CDCV 6208     // [4096] col_hidden . w_cv_col
#define WS_RDVC 10304    // [4096] row_next . w_vc_row
#define WS_CDVC 14400    // [4096] col_hidden . w_vc_col
#define WS_PART 18496    // [32][4096*64] j-split partials (32 MB)

__device__ __forceinline__ float sigf(float x) {
    return 1.0f / (1.0f + __expf(-x));
}

// async global->LDS, 16B per lane. LDS dest is wave-uniform base + lane*16
// (hardware semantics); global src is per-lane. Tracked by vmcnt; the
// compiler's s_waitcnt before __syncthreads() drains it.
#define AS1 __attribute__((address_space(1)))
#define AS3 __attribute__((address_space(3)))
__device__ __forceinline__ void gl_lds16(const float* g, float* l) {
    __builtin_amdgcn_global_load_lds((const AS1 void*)g, (AS3 void*)l, 16, 0, 0);
}

// score-tile swizzle within a 32-f4 row: FMA reads rows {16w+r,+4,+8,+12} in
// one instruction; row base is bank-aligned (128 floats/row = 4x bank wrap),
// so XOR the f4-col with ((row>>2)&3)<<1 -> the 4 rows hit 4 distinct bank
// groups. Bijective within each row.
#define SSWZ_F4C(row, f4c) ((f4c) ^ ((((row) >> 2) & 3) << 1))

// ---------------------------------------------------------------------------
// Attention body over 4096 nodes (one 256-thread block handles 256 nodes).
__device__ __forceinline__ void attn_body(
    int blk, int t, const float* __restrict__ X, const float* __restrict__ supp,
    const float* __restrict__ obj, const float* __restrict__ wat,
    const float* __restrict__ bat, float* __restrict__ accP,
    const float* __restrict__ wextra, float* __restrict__ dextra,
    float* sA, float* sAcc)
{
    const int i = blk * 256 + t;
    float od = 0.f;
    for (int h = 0; h < 64; ++h) od += obj[h] * wat[66 + h];
    float x = bat[0] + od + supp[i*2] * wat[64] + supp[i*2+1] * wat[65];
    const f4* Xr = (const f4*)(X + i*64);
    f4 xd = 0.f, dd = 0.f;
    #pragma unroll
    for (int q = 0; q < 16; ++q) {
        f4 xv = Xr[q];
        xd += xv * ((const f4*)wat)[q];
        if (wextra) dd += xv * ((const f4*)wextra)[q];
    }
    x += xd.x + xd.y + xd.z + xd.w;
    if (dextra) dextra[i] = dd.x + dd.y + dd.z + dd.w;
    sA[t] = sigf(x);
    if (t < 64) sAcc[t] = 0.f;
    __syncthreads();
    const int w = t >> 6, h = t & 63;
    const int base = blk * 256 + w * 64;
    float partial = 0.f;
    for (int j = 0; j < 64; ++j)
        partial += sA[w*64 + j] * X[(base + j)*64 + h];
    atomicAdd(&sAcc[h], partial);
    __syncthreads();
    if (t < 64) accP[blk*64 + t] = sAcc[t];
}

// ---------------------------------------------------------------------------
// Front kernel: 3072 dot blocks + 16 small-copy blocks + 16 v->o attention blocks.
__global__ __launch_bounds__(256) void k_front(
    const float* __restrict__ col_hidden, const float* __restrict__ row_hidden,
    const float* __restrict__ w_cv_col, const float* __restrict__ w_vc_col,
    const float* __restrict__ w_cv_row,
    float* __restrict__ cdcv, float* __restrict__ cdvc, float* __restrict__ rdcv,
    const float* __restrict__ vo_supp, const float* __restrict__ co_supp,
    float* __restrict__ out_vo, float* __restrict__ out_co,
    const float* __restrict__ obj_hidden, const float* __restrict__ w_attn_vo,
    const float* __restrict__ b_attn_vo, float* __restrict__ voP)
{
    __shared__ float sA[256];
    __shared__ float sAcc[64];
    const int t = threadIdx.x;
    if (blockIdx.x < 3072) {
        const int gw = blockIdx.x * 4 + (t >> 6);
        const int lane = t & 63;
        const int which = gw >> 12;       // 0,1,2
        const int row = gw & 4095;
        const float* x; const float* w; float* dst;
        if (which == 0)      { x = col_hidden; w = w_cv_col; dst = cdcv; }
        else if (which == 1) { x = col_hidden; w = w_vc_col; dst = cdvc; }
        else                 { x = row_hidden; w = w_cv_row; dst = rdcv; }
        float v = x[row * 64 + lane] * w[lane];
        #pragma unroll
        for (int off = 32; off; off >>= 1) v += __shfl_down(v, off, 64);
        if (lane == 0) dst[row] = v;
        return;
    }
    if (blockIdx.x < 3088) {
        const int idx = (blockIdx.x - 3072) * 256 + t;   // 0..4095 f4 units
        if (idx < 2048) ((f4*)out_vo)[idx] = ((const f4*)vo_supp)[idx];
        else            ((f4*)out_co)[idx - 2048] = ((const f4*)co_supp)[idx - 2048];
        return;
    }
    attn_body(blockIdx.x - 3088, t, col_hidden, vo_supp, obj_hidden,
              w_attn_vo, b_attn_vo, voP, nullptr, nullptr, sA, sAcc);
}

// ---------------------------------------------------------------------------
// Standalone c->o attention (16 blocks), with fused rowdot_vc.
__global__ __launch_bounds__(256) void k_attn(
    const float* __restrict__ X, const float* __restrict__ supp,
    const float* __restrict__ obj, const float* __restrict__ wat,
    const float* __restrict__ bat, float* __restrict__ accP,
    const float* __restrict__ wextra, float* __restrict__ dextra)
{
    __shared__ float sA[256];
    __shared__ float sAcc[64];
    attn_body(blockIdx.x, threadIdx.x, X, supp, obj, wat, bat, accP,
              wextra, dextra, sA, sAcc);
}

// ---------------------------------------------------------------------------
// Big fused kernel: masked pairwise sigmoid scores + score @ B + supp passthrough.
//   out(i,h) = sum_j [supp0(i,j)!=0] sig(rdot[i]+cdot[j]+w0*supp0+w1*supp1+b) * B(j,h)
// R3 theory: reg-staged loads (R0/R2 structures) serialize per-wave at HBM
// latency -> ~2 TB/s invariant. This version stages BOTH supp planes via
// global_load_lds (deep vmcnt queue, zero register pressure), reads them back
// from LDS for the passthrough stores (plain stores, same path as the 6.3 TB/s
// copy), computes scores IN-PLACE over the supp0 LDS region (swizzled), then
// reuses the dead supp1 region for the full 128-row B tile.
// Tile 64 rows x 128 j. LDS = 2 x 32 KB -> 2 blocks/CU. 32 j-splits.
// grid = 64*32 + 1 = 2049.
__global__ __launch_bounds__(256, 2) void k_big(
    const float* __restrict__ supp0, const float* __restrict__ supp1,
    const float* __restrict__ Bm,
    const float* __restrict__ rdot, const float* __restrict__ cdot,
    const float* __restrict__ wsup, const float* __restrict__ bias,
    float* __restrict__ part, float* __restrict__ pass0, float* __restrict__ pass1,
    const float* __restrict__ objL, const float* __restrict__ objRp,
    const float* __restrict__ Wobj, float* __restrict__ objDst)
{
    __shared__ __align__(16) float lds0[64*128];   // supp0 -> score tile (32 KB)
    __shared__ __align__(16) float lds1[64*128];   // supp1 -> B tile [128][64] (32 KB)
    const int t = threadIdx.x;

    if (blockIdx.x == 2048) {
        // obj update: objDst[h] = relu([objL | sum_b objRp[b]] @ Wobj)
        if (t < 64) {
            float r = 0.f;
            for (int b = 0; b < 16; ++b) r += objRp[b*64 + t];
            lds0[t] = r;
        }
        __syncthreads();
        if (t < 64) {
            float acc = 0.f;
            for (int k = 0; k < 64; ++k) acc += objL[k] * Wobj[k*64 + t];
            for (int k = 0; k < 64; ++k) acc += lds0[k] * Wobj[(64+k)*64 + t];
            objDst[t] = fmaxf(acc, 0.f);
        }
        return;
    }

    const int bi = blockIdx.x >> 5;       // row-block 0..63
    const int bj = blockIdx.x & 31;       // j-split 0..31 (fast: j-sweep within band)
    const int i0 = bi * 64;
    const int jt0 = bj * 128;
    const int w = t >> 6, lane = t & 63;
    const float w0 = wsup[0], w1 = wsup[1], bv = bias[0];

    // ---- phase 1: issue all supp staging (16 gl_lds per wave, no regs) ----
    // row-pair p: rows 2p,2p+1; one instruction moves 1 KB (2 x 512 B rows).
    for (int k = 0; k < 8; ++k) {
        const int p = w * 8 + k;          // 0..31
        const size_t g = (size_t)(i0 + 2*p + (lane >> 5)) * 4096 + jt0 + (lane & 31) * 4;
        gl_lds16(supp0 + g, lds0 + p * 256);
        gl_lds16(supp1 + g, lds1 + p * 256);
    }
    __syncthreads();   // drains vmcnt: supp tiles resident

    // ---- phase 2: passthrough stores + in-place score ----
    // Each wave owns row-pairs p = q*4+w (disjoint): LDS read-before-write
    // within the same wave instruction stream -> in-place is race-free.
    {
        const int f4c = lane & 31;
        const f4 cd = *(const f4*)(cdot + jt0 + f4c * 4);
        for (int q = 0; q < 8; ++q) {
            const int p = q * 4 + w;
            const int row = 2 * p + (lane >> 5);   // local row 0..63
            f4 a0 = *(const f4*)(lds0 + p * 256 + lane * 4);
            f4 a1 = *(const f4*)(lds1 + p * 256 + lane * 4);
            const size_t g = (size_t)(i0 + row) * 4096 + jt0 + f4c * 4;
            *(f4*)(pass0 + g) = a0;               // plain stores (copy-kernel path)
            *(f4*)(pass1 + g) = a1;
            const float rd = rdot[i0 + row];
            f4 lg = rd + cd + w0 * a0 + w1 * a1 + bv;
            f4 s;
            s.x = (a0.x != 0.f) ? sigf(lg.x) : 0.f;
            s.y = (a0.y != 0.f) ? sigf(lg.y) : 0.f;
            s.z = (a0.z != 0.f) ? sigf(lg.z) : 0.f;
            s.w = (a0.w != 0.f) ? sigf(lg.w) : 0.f;
            *(f4*)(lds0 + row * 128 + SSWZ_F4C(row, f4c) * 4) = s;
        }
    }
    __syncthreads();   // scores complete; supp1 region now dead

    // ---- phase 3: stage B tile [128 j-rows][64 h] into lds1 ----
    for (int k = 0; k < 8; ++k) {
        const int c = w * 8 + k;          // 1 KB chunk = 4 B-rows, 0..31
        gl_lds16(Bm + (size_t)(jt0 + c * 4) * 64 + lane * 4, lds1 + c * 256);
    }
    __syncthreads();   // drains vmcnt: B resident

    // ---- phase 4: rank-128 update, 4 rows x 4 h per thread ----
    const int ilb = t >> 4;               // 0..15 -> rows ilb*4..+3
    const int hf4 = t & 15;               // f4-column of output h
    const int sw  = (ilb & 3) << 1;       // == ((row>>2)&3)<<1 for rows ilb*4+r
    f4 acc0 = 0.f, acc1 = 0.f, acc2 = 0.f, acc3 = 0.f;
    #pragma unroll 4
    for (int jf = 0; jf < 32; ++jf) {
        const int jj = jf * 4;
        f4 b0 = *(const f4*)(lds1 + (jj + 0) * 64 + hf4 * 4);
        f4 b1 = *(const f4*)(lds1 + (jj + 1) * 64 + hf4 * 4);
        f4 b2 = *(const f4*)(lds1 + (jj + 2) * 64 + hf4 * 4);
        f4 b3 = *(const f4*)(lds1 + (jj + 3) * 64 + hf4 * 4);
        const int sf = (jf ^ sw) * 4;
        { f4 s = *(const f4*)(lds0 + (ilb*4 + 0) * 128 + sf); acc0 += s.x*b0 + s.y*b1 + s.z*b2 + s.w*b3; }
        { f4 s = *(const f4*)(lds0 + (ilb*4 + 1) * 128 + sf); acc1 += s.x*b0 + s.y*b1 + s.z*b2 + s.w*b3; }
        { f4 s = *(const f4*)(lds0 + (ilb*4 + 2) * 128 + sf); acc2 += s.x*b0 + s.y*b1 + s.z*b2 + s.w*b3; }
        { f4 s = *(const f4*)(lds0 + (ilb*4 + 3) * 128 + sf); acc3 += s.x*b0 + s.y*b1 + s.z*b2 + s.w*b3; }
    }
    // partials: regular stores (re-read next dispatch — let L2/L3 keep them)
    float* pb = part + (size_t)bj * 262144 + (size_t)i0 * 64;
    *(f4*)(pb + (ilb*4 + 0)*64 + hf4*4) = acc0;
    *(f4*)(pb + (ilb*4 + 1)*64 + hf4*4) = acc1;
    *(f4*)(pb + (ilb*4 + 2)*64 + hf4*4) = acc2;
    *(f4*)(pb + (ilb*4 + 3)*64 + hf4*4) = acc3;
}

// ---------------------------------------------------------------------------
// Two-layer node update with fused 32-way partial reduction:
//   accin[n] = sum_j part[j][n]
//   mid = relu([objx | base[n]] @ W1);  dst[n] = relu([mid | accin[n]] @ W2)
// One wave per node row; grid = 1024 blocks x 256.
__global__ __launch_bounds__(256) void k_mlp2(
    const float* __restrict__ objx, const float* __restrict__ base,
    const float* __restrict__ W1, const float* __restrict__ part,
    const float* __restrict__ W2, float* __restrict__ dst)
{
    __shared__ float mid[4][64];
    __shared__ float accs[4][64];
    const int t = threadIdx.x, w = t >> 6, h = t & 63;
    const int n = blockIdx.x * 4 + w;
    float v = 0.f;
    #pragma unroll 8
    for (int j = 0; j < 32; ++j) v += part[(size_t)j * 262144 + n*64 + h];
    accs[w][h] = v;
    float m = 0.f;
    for (int k = 0; k < 64; ++k) m += objx[k] * W1[k*64 + h];
    for (int k = 0; k < 64; ++k) m += base[n*64 + k] * W1[(64+k)*64 + h];
    mid[w][h] = fmaxf(m, 0.f);
    __syncthreads();
    float o = 0.f;
    for (int k = 0; k < 64; ++k) o += mid[w][k] * W2[k*64 + h];
    for (int k = 0; k < 64; ++k) o += accs[w][k] * W2[(64+k)*64 + h];
    dst[n*64 + h] = fmaxf(o, 0.f);
}

extern "C" void kernel_launch(void* const* d_in, const int* in_sizes, int n_in,
                              void* d_out, int out_size, void* d_ws, size_t ws_size,
                              hipStream_t stream)
{
    const float* col_hidden = (const float*)d_in[0];
    const float* row_hidden = (const float*)d_in[1];
    const float* obj_hidden = (const float*)d_in[2];
    const float* cv_supp    = (const float*)d_in[3];
    const float* vc_supp    = (const float*)d_in[4];
    const float* vo_supp    = (const float*)d_in[5];
    const float* co_supp    = (const float*)d_in[6];
    const float* W_vo       = (const float*)d_in[7];
    const float* W_oc       = (const float*)d_in[8];
    const float* W_vc       = (const float*)d_in[9];
    const float* W_co       = (const float*)d_in[10];
    const float* W_ov       = (const float*)d_in[11];
    const float* W_cv       = (const float*)d_in[12];
    const float* w_attn_vo  = (const float*)d_in[13];
    const float* b_attn_vo  = (const float*)d_in[14];
    const float* w_attn_co  = (const float*)d_in[15];
    const float* b_attn_co  = (const float*)d_in[16];
    const float* w_cv_col   = (const float*)d_in[17];
    const float* w_cv_supp  = (const float*)d_in[18];
    const float* w_cv_row   = (const float*)d_in[19];
    const float* b_cv       = (const float*)d_in[20];
    const float* w_vc_row   = (const float*)d_in[21];
    const float* w_vc_supp  = (const float*)d_in[22];
    const float* w_vc_col   = (const float*)d_in[23];
    const float* b_vc       = (const float*)d_in[24];

    float* out = (float*)d_out;
    float* ws  = (float*)d_ws;

    // 1) dots + small passthrough + v->o attention partials
    k_front<<<3104, 256, 0, stream>>>(col_hidden, row_hidden, w_cv_col, w_vc_col, w_cv_row,
                                      ws + WS_CDCV, ws + WS_CDVC, ws + WS_RDCV,
                                      vo_supp, co_supp, out + OUT_VO, out + OUT_CO,
                                      obj_hidden, w_attn_vo, b_attn_vo, ws + WS_VO_P);
    // 2) v->c big masked matmul (+ fused cv_supp passthrough, + obj v->o update)
    k_big<<<2049, 256, 0, stream>>>(cv_supp, cv_supp + PLANE, col_hidden,
                                    ws + WS_RDCV, ws + WS_CDCV, w_cv_supp, b_cv,
                                    ws + WS_PART, out + OUT_CV, out + OUT_CV + PLANE,
                                    obj_hidden, ws + WS_VO_P, W_vo, ws + WS_OBJ1);
    // 3) row_next = relu([relu([obj1|row_hidden]W_oc) | v_out] W_vc)
    k_mlp2<<<1024, 256, 0, stream>>>(ws + WS_OBJ1, row_hidden, W_oc, ws + WS_PART, W_vc,
                                     out + OUT_ROW);
    // 4) c->o attention partials (+ fused rowdot_vc over row_next)
    k_attn<<<16, 256, 0, stream>>>(out + OUT_ROW, co_supp, ws + WS_OBJ1, w_attn_co, b_attn_co,
                                   ws + WS_CO_P, w_vc_row, ws + WS_RDVC);
    // 5) c->v big masked matmul (+ fused vc_supp passthrough, + obj c->o update)
    k_big<<<2049, 256, 0, stream>>>(vc_supp, vc_supp + PLANE, out + OUT_ROW,
                                    ws + WS_CDVC, ws + WS_RDVC, w_vc_supp, b_vc,
                                    ws + WS_PART, out + OUT_VC, out + OUT_VC + PLANE,
                                    ws + WS_OBJ1, ws + WS_CO_P, W_co, out + OUT_OBJ);
    // 6) col_next = relu([relu([obj|col_hidden]W_ov) | c_out] W_cv)
    k_mlp2<<<1024, 256, 0, stream>>>(out + OUT_OBJ, col_hidden, W_ov, ws + WS_PART, W_cv,
                                     out + OUT_COL);
}